// Round 8
// baseline (97.514 us; speedup 1.0000x reference)
//
#include <hip/hip_runtime.h>

#define IMG_H 8192
#define IMG_W 8192
#define TILE_W 256
#define TILE_H 32
#define ST_ROWS (TILE_H + 2)                 // 34 staged rows
#define ST_COLS 264                          // image cols X0-4 .. X0+259
#define CHUNKS_PER_ROW (ST_COLS / 4)         // 66
#define N_CHUNKS (ST_ROWS * CHUNKS_PER_ROW)  // 2244
#define K_TILES 8                            // vertical tiles per block
#define GRID_X (IMG_W / TILE_W)              // 32
#define GRID_YG (IMG_H / (TILE_H * K_TILES)) // 32

typedef float floatx4 __attribute__((ext_vector_type(4)));

__global__ __launch_bounds__(256) void conv3x3_pipe(const float* __restrict__ img,
                                                    const float* __restrict__ ker,
                                                    float* __restrict__ out) {
    __shared__ float ldsA[ST_ROWS * ST_COLS];   // 35,904 B each; double-buffered -> 71.8 KB, 2 blocks/CU
    __shared__ float ldsB[ST_ROWS * ST_COLS];

    const int bx  = blockIdx.x & (GRID_X - 1);
    const int byg = blockIdx.x >> 5;
    const int X0  = bx * TILE_W;
    const int Y0b = byg * (TILE_H * K_TILES);
    const int t   = threadIdx.x;
    const int wv  = t >> 6;
    const int ln  = t & 63;
    const int colBase = 4 * ln;

    const bool eL = (X0 == 0), eR = (X0 == IMG_W - TILE_W);

    const float w00 = ker[0], w01 = ker[1], w02 = ker[2];
    const float w10 = ker[3], w11 = ker[4], w12 = ker[5];
    const float w20 = ker[6], w21 = ker[7], w22 = ker[8];

    // ---- stage one tile (clamped addresses; exactly 9 wave-instrs per wave, uniform) ----
    auto stage = [&](float* buf, int Y0_) {
        #pragma unroll
        for (int pass = 0; pass < 9; ++pass) {
            const int chunk = pass * 256 + t;
            if (chunk < N_CHUNKS) {           // pass 8: every wave still has active lanes -> 9 instrs/wave
                const int r  = chunk / CHUNKS_PER_ROW;
                const int c4 = chunk - r * CHUNKS_PER_ROW;
                int gy = Y0_ - 1 + r;  gy = min(max(gy, 0), IMG_H - 1);
                int gx = X0 - 4 + c4 * 4;  gx = min(max(gx, 0), IMG_W - 4);
                __builtin_amdgcn_global_load_lds(
                    (const __attribute__((address_space(1))) void*)(img + (size_t)gy * IMG_W + gx),
                    (__attribute__((address_space(3))) void*)(buf + chunk * 4), 16, 0, 0);
            }
        }
    };

    // ---- zero-fixup halo cells of a staged tile (call only when fT|fB|eL|eR) ----
    auto fixup = [&](float* buf, bool fT, bool fB) {
        const floatx4 z = {0.f, 0.f, 0.f, 0.f};
        if (fT && t < CHUNKS_PER_ROW) *(floatx4*)&buf[t * 4] = z;
        if (fB && t < CHUNKS_PER_ROW) *(floatx4*)&buf[(ST_ROWS - 1) * ST_COLS + t * 4] = z;
        if (eL && t < ST_ROWS) *(floatx4*)&buf[t * ST_COLS + 0] = z;
        if (eR && t < ST_ROWS) *(floatx4*)&buf[t * ST_COLS + 260] = z;
        asm volatile("s_waitcnt lgkmcnt(0)" ::: "memory");
        __builtin_amdgcn_s_barrier();
    };

    // ---- compute 4 output rows from staged rows oyB..oyB+5 (register row rotation) ----
    auto compute4 = [&](const float* buf, int Y0_, int oyB) {
        #define LDROW(r, A, B, C) do {                                   \
            const float* p_ = &buf[(r) * ST_COLS + colBase];             \
            A = *(const floatx4*)p_;                                     \
            B = *(const floatx4*)(p_ + 4);                               \
            C = *(const floatx4*)(p_ + 8);                               \
        } while (0)
        floatx4 a0, b0, c0, a1, b1, c1;
        LDROW(oyB + 0, a0, b0, c0);
        LDROW(oyB + 1, a1, b1, c1);
        #pragma unroll
        for (int oy = 0; oy < 4; ++oy) {
            floatx4 a2, b2, c2;
            LDROW(oyB + oy + 2, a2, b2, c2);
            float t0[6] = {a0.w, b0.x, b0.y, b0.z, b0.w, c0.x};
            float t1[6] = {a1.w, b1.x, b1.y, b1.z, b1.w, c1.x};
            float t2[6] = {a2.w, b2.x, b2.y, b2.z, b2.w, c2.x};
            floatx4 res;
            #pragma unroll
            for (int j = 0; j < 4; ++j) {
                res[j] = w00 * t0[j] + w01 * t0[j + 1] + w02 * t0[j + 2]
                       + w10 * t1[j] + w11 * t1[j + 1] + w12 * t1[j + 2]
                       + w20 * t2[j] + w21 * t2[j + 1] + w22 * t2[j + 2];
            }
            const int y_ = Y0_ + oyB + oy;
            __builtin_nontemporal_store(res, (floatx4*)(out + (size_t)y_ * IMG_W + X0 + colBase));
            a0 = a1; b0 = b1; c0 = c1;
            a1 = a2; b1 = b2; c1 = c2;
        }
        #undef LDROW
    };

    float* cur = ldsA;
    float* nxt = ldsB;

    // ---- prologue: stage tile 0, full drain (one-time) ----
    stage(cur, Y0b);
    asm volatile("s_waitcnt vmcnt(0)" ::: "memory");
    __builtin_amdgcn_s_barrier();
    __builtin_amdgcn_sched_barrier(0);
    {
        const bool fT = (Y0b == 0);
        if (fT | eL | eR) fixup(cur, fT, false);
    }

    // ---- pipelined tile loop: stage(t+1) in flight under compute(t) ----
    for (int tt = 0; tt < K_TILES; ++tt) {
        const int Y0 = Y0b + tt * TILE_H;

        if (tt + 1 < K_TILES) stage(nxt, Y0 + TILE_H);   // 9 instrs, lands during compute below

        compute4(cur, Y0, 4 * wv);          // rows 0..15 of tile (wave wv -> 4 rows)
        compute4(cur, Y0, 16 + 4 * wv);     // rows 16..31

        if (tt + 1 < K_TILES) {
            // outstanding: [<=8 stores(tt-1)] + 9 stage(tt+1) + 8 stores(tt); vmcnt(8)
            // drains through the 9 stage instrs (in-order retirement), leaves stores in flight.
            __builtin_amdgcn_sched_barrier(0);
            asm volatile("s_waitcnt vmcnt(8)" ::: "memory");
            __builtin_amdgcn_s_barrier();
            __builtin_amdgcn_sched_barrier(0);
            const int Y0n = Y0 + TILE_H;
            const bool fB = (Y0n == IMG_H - TILE_H);
            if (fB | eL | eR) fixup(nxt, false, fB);
            float* tmp = cur; cur = nxt; nxt = tmp;
        }
    }
}

extern "C" void kernel_launch(void* const* d_in, const int* in_sizes, int n_in,
                              void* d_out, int out_size, void* d_ws, size_t ws_size,
                              hipStream_t stream) {
    const float* img = (const float*)d_in[0];
    const float* ker = (const float*)d_in[1];
    float* out = (float*)d_out;

    const int grid = GRID_X * GRID_YG;   // 1024 blocks, 2 scheduling rounds at 2 blocks/CU
    conv3x3_pipe<<<grid, 256, 0, stream>>>(img, ker, out);
}

// Round 9
// 89.666 us; speedup vs baseline: 1.0875x; 1.0875x over previous
//
#include <hip/hip_runtime.h>

#define IMG_H 8192
#define IMG_W 8192
#define TILE_W 256
#define TILE_H 32
#define ST_ROWS (TILE_H + 2)                 // 34 staged rows
#define ST_COLS 264                          // staged floats/row: image cols X0-4 .. X0+259
#define CHUNKS_PER_ROW (ST_COLS / 4)         // 66 x 16B chunks
#define N_CHUNKS (ST_ROWS * CHUNKS_PER_ROW)  // 2244
#define GRID_X (IMG_W / TILE_W)              // 32
#define GRID_Y (IMG_H / TILE_H)              // 256

typedef float floatx4 __attribute__((ext_vector_type(4)));

__global__ __launch_bounds__(256) void conv3x3_lds(const float* __restrict__ img,
                                                   const float* __restrict__ ker,
                                                   float* __restrict__ out) {
    // Linear LDS: chunk c occupies bytes [c*16, c*16+16) = row c/66, cols 4*(c%66)..+3
    __shared__ float lds[ST_ROWS * ST_COLS];   // 35,904 B -> 4 blocks/CU

    const int bx = blockIdx.x & (GRID_X - 1);
    const int by = blockIdx.x >> 5;
    const int X0 = bx * TILE_W;
    const int Y0 = by * TILE_H;
    const int t  = threadIdx.x;

    // ---- stage: 2244 async 16B chunks, clamped addresses (edges fixed up below) ----
    #pragma unroll
    for (int pass = 0; pass < 9; ++pass) {
        const int chunk = pass * 256 + t;
        if (chunk < N_CHUNKS) {
            const int r  = chunk / CHUNKS_PER_ROW;
            const int c4 = chunk % CHUNKS_PER_ROW;
            int gy = Y0 - 1 + r;
            gy = min(max(gy, 0), IMG_H - 1);
            int gx = X0 - 4 + c4 * 4;
            gx = min(max(gx, 0), IMG_W - 4);
            const float* src = img + (size_t)gy * IMG_W + gx;
            float* dst = &lds[chunk * 4];
            __builtin_amdgcn_global_load_lds(
                (const __attribute__((address_space(1))) void*)src,
                (__attribute__((address_space(3))) void*)dst,
                16, 0, 0);
        }
    }
    asm volatile("s_waitcnt vmcnt(0)" ::: "memory");
    __syncthreads();

    // ---- zero-fixup of out-of-image halo cells (block-uniform conditions) ----
    const bool eT = (Y0 == 0), eB = (Y0 == IMG_H - TILE_H);
    const bool eL = (X0 == 0), eR = (X0 == IMG_W - TILE_W);
    if (eT | eB | eL | eR) {
        const floatx4 z = {0.f, 0.f, 0.f, 0.f};
        if (eT && t < CHUNKS_PER_ROW) *(floatx4*)&lds[t * 4] = z;                           // staged row 0 = image row -1
        if (eB && t < CHUNKS_PER_ROW) *(floatx4*)&lds[(ST_ROWS - 1) * ST_COLS + t * 4] = z; // staged row 33 = image row 8192
        if (eL && t < ST_ROWS) *(floatx4*)&lds[t * ST_COLS + 0] = z;                        // staged cols 0..3 = image cols -4..-1
        if (eR && t < ST_ROWS) *(floatx4*)&lds[t * ST_COLS + 260] = z;                      // staged cols 260..263 = image cols 8192..
        __syncthreads();
    }

    // ---- compute: wave w -> output rows 8w..8w+7; lane -> 4 px ----
    const float w00 = ker[0], w01 = ker[1], w02 = ker[2];
    const float w10 = ker[3], w11 = ker[4], w12 = ker[5];
    const float w20 = ker[6], w21 = ker[7], w22 = ker[8];

    const int wv = t >> 6;
    const int ln = t & 63;
    const int oyBase = wv * 8;
    const int colBase = 4 * ln;   // staged col of first output px's left neighbor block

    // three overlapping b128 per row: vL(cols 4ln..+3), vC(+4..+7), vR(+8..+11) — lane stride 16B, conflict-free
    #define LDROW(r, A, B, C) do {                                     \
        const float* p_ = &lds[(r) * ST_COLS + colBase];               \
        A = *(const floatx4*)p_;                                       \
        B = *(const floatx4*)(p_ + 4);                                 \
        C = *(const floatx4*)(p_ + 8);                                 \
    } while (0)

    floatx4 a0, b0, c0, a1, b1, c1;
    LDROW(oyBase + 0, a0, b0, c0);
    LDROW(oyBase + 1, a1, b1, c1);

    #pragma unroll
    for (int oy = 0; oy < 8; ++oy) {
        floatx4 a2, b2, c2;
        LDROW(oyBase + oy + 2, a2, b2, c2);

        // window: staged rows oy..oy+2 = image rows y-1,y,y+1 for y = Y0+oyBase+oy
        float t0[6] = {a0.w, b0.x, b0.y, b0.z, b0.w, c0.x};
        float t1[6] = {a1.w, b1.x, b1.y, b1.z, b1.w, c1.x};
        float t2[6] = {a2.w, b2.x, b2.y, b2.z, b2.w, c2.x};

        floatx4 res;
        #pragma unroll
        for (int j = 0; j < 4; ++j) {
            res[j] = w00 * t0[j] + w01 * t0[j + 1] + w02 * t0[j + 2]
                   + w10 * t1[j] + w11 * t1[j + 1] + w12 * t1[j + 2]
                   + w20 * t2[j] + w21 * t2[j + 1] + w22 * t2[j + 2];
        }

        const int y = Y0 + oyBase + oy;
        __builtin_nontemporal_store(res, (floatx4*)(out + (size_t)y * IMG_W + X0 + colBase));

        a0 = a1; b0 = b1; c0 = c1;
        a1 = a2; b1 = b2; c1 = c2;
    }
    #undef LDROW
}

extern "C" void kernel_launch(void* const* d_in, const int* in_sizes, int n_in,
                              void* d_out, int out_size, void* d_ws, size_t ws_size,
                              hipStream_t stream) {
    const float* img = (const float*)d_in[0];
    const float* ker = (const float*)d_in[1];
    float* out = (float*)d_out;

    const int grid = GRID_X * GRID_Y;   // 8192 blocks; vertical halo-sharing neighbors (b±32) land on the same XCD (32%8==0)
    conv3x3_lds<<<grid, 256, 0, stream>>>(img, ker, out);
}